// Round 1
// baseline (2950.600 us; speedup 1.0000x reference)
//
#include <hip/hip_runtime.h>
#include <math.h>

// GCN 2-layer: out = A_norm @ relu(A_norm @ x @ W1 + b1) @ W2 + b2
// where A_norm = D_dst^{-1/2} (A + I) D_src^{-1/2}
// Key restructuring: aggregate in 128-dim space for BOTH layers:
//   layer1: aggregate x (128d), then GEMM 128->256 (+bias, relu)
//   layer2: t = h1 @ W2 (256->128) scaled by out_isqrt, then aggregate t (128d),
//           then scale by in_isqrt and add b2.

constexpr int IN_DIM  = 128;
constexpr int HID_DIM = 256;
constexpr int OUT_DIM = 128;

#define DIV_UP(a, b) (((a) + (b) - 1) / (b))

__global__ void k_init_deg(int* __restrict__ deg_src, int* __restrict__ deg_dst, int n) {
    int i = blockIdx.x * blockDim.x + threadIdx.x;
    if (i < n) { deg_src[i] = 1; deg_dst[i] = 1; }  // self-loop contributes 1
}

__global__ void k_count_deg(const int* __restrict__ src, const int* __restrict__ dst,
                            int* __restrict__ deg_src, int* __restrict__ deg_dst, int e) {
    int i = blockIdx.x * blockDim.x + threadIdx.x;
    if (i < e) {
        atomicAdd(&deg_src[src[i]], 1);
        atomicAdd(&deg_dst[dst[i]], 1);
    }
}

__global__ void k_isqrt(const int* __restrict__ deg_src, const int* __restrict__ deg_dst,
                        float* __restrict__ out_isqrt, float* __restrict__ in_isqrt, int n) {
    int i = blockIdx.x * blockDim.x + threadIdx.x;
    if (i < n) {
        out_isqrt[i] = 1.0f / sqrtf((float)deg_src[i]);  // deg >= 1 always
        in_isqrt[i]  = 1.0f / sqrtf((float)deg_dst[i]);
    }
}

// m[i][:] = feat[i][:] * scale[i]   (the self-loop contribution, zero-init fused away)
template <int DQ>  // DQ = feature dim / 4
__global__ void k_scale_init(const float* __restrict__ feat, const float* __restrict__ scale,
                             float* __restrict__ m, int total) {
    int t = blockIdx.x * blockDim.x + threadIdx.x;
    if (t >= total) return;
    int row = t / DQ;
    float4 v = reinterpret_cast<const float4*>(feat)[t];
    float s = scale[row];
    v.x *= s; v.y *= s; v.z *= s; v.w *= s;
    reinterpret_cast<float4*>(m)[t] = v;
}

// accum[dst[e]][:] += feat[src[e]][:] * (HAS_SCALE ? scale[src[e]] : 1)
template <int DQ, bool HAS_SCALE>
__global__ void k_scatter(const float* __restrict__ feat, float* __restrict__ accum,
                          const int* __restrict__ src, const int* __restrict__ dst,
                          const float* __restrict__ scale, int e) {
    int t = blockIdx.x * blockDim.x + threadIdx.x;
    if (t >= e * DQ) return;
    int eid = t / DQ;
    int c   = t - eid * DQ;
    int s = src[eid];
    int d = dst[eid];
    float4 v = reinterpret_cast<const float4*>(feat)[(size_t)s * DQ + c];
    if (HAS_SCALE) {
        float sc = scale[s];
        v.x *= sc; v.y *= sc; v.z *= sc; v.w *= sc;
    }
    float* p = accum + ((size_t)d * DQ + c) * 4;
    atomicAdd(p + 0, v.x);
    atomicAdd(p + 1, v.y);
    atomicAdd(p + 2, v.z);
    atomicAdd(p + 3, v.w);
}

// C = epilogue( (rowscale_in ⊙ A) @ B ), A: MxK row-major, B: KxNc row-major.
// epilogue: + bias (if bias), relu (if do_relu), * rowscale_out[row] (if rowscale_out).
// Dual-store to C2 if non-null.
__global__ __launch_bounds__(256) void k_gemm(
    const float* __restrict__ A, const float* __restrict__ B,
    const float* __restrict__ bias, const float* __restrict__ rowscale_in,
    const float* __restrict__ rowscale_out,
    float* __restrict__ C, float* __restrict__ C2,
    int M, int K, int Nc, int do_relu) {
    __shared__ float As[32][64];  // k-major
    __shared__ float Bs[32][64];

    const int tid = threadIdx.x;
    const int tx = tid & 15;   // -> 4 cols
    const int ty = tid >> 4;   // -> 4 rows
    const int row0 = blockIdx.y * 64;
    const int col0 = blockIdx.x * 64;

    float acc[4][4] = {};

    for (int kb = 0; kb < K; kb += 32) {
        // A tile: 64 rows x 32 k. Each thread: one float4 along K, transposed store.
#pragma unroll
        for (int l = 0; l < 2; ++l) {
            int li = tid + l * 256;
            int r = li >> 3;       // 0..63
            int kq = li & 7;       // float4 index along k
            int row = row0 + r;
            float4 v = make_float4(0.f, 0.f, 0.f, 0.f);
            if (row < M) {
                v = *reinterpret_cast<const float4*>(&A[(size_t)row * K + kb + kq * 4]);
                if (rowscale_in) {
                    float s = rowscale_in[row];
                    v.x *= s; v.y *= s; v.z *= s; v.w *= s;
                }
            }
            As[kq * 4 + 0][r] = v.x;
            As[kq * 4 + 1][r] = v.y;
            As[kq * 4 + 2][r] = v.z;
            As[kq * 4 + 3][r] = v.w;
        }
        // B tile: 32 k x 64 cols, direct float4 store.
#pragma unroll
        for (int l = 0; l < 2; ++l) {
            int li = tid + l * 256;
            int c4 = li & 15;
            int kk = li >> 4;
            float4 v = *reinterpret_cast<const float4*>(&B[(size_t)(kb + kk) * Nc + col0 + c4 * 4]);
            *reinterpret_cast<float4*>(&Bs[kk][c4 * 4]) = v;
        }
        __syncthreads();
#pragma unroll
        for (int k = 0; k < 32; ++k) {
            float4 av = *reinterpret_cast<float4*>(&As[k][ty * 4]);
            float4 bv = *reinterpret_cast<float4*>(&Bs[k][tx * 4]);
            float a_[4] = {av.x, av.y, av.z, av.w};
            float b_[4] = {bv.x, bv.y, bv.z, bv.w};
#pragma unroll
            for (int i = 0; i < 4; ++i)
#pragma unroll
                for (int j = 0; j < 4; ++j)
                    acc[i][j] += a_[i] * b_[j];
        }
        __syncthreads();
    }

    float bias_v[4] = {0.f, 0.f, 0.f, 0.f};
    if (bias) {
#pragma unroll
        for (int j = 0; j < 4; ++j) bias_v[j] = bias[col0 + tx * 4 + j];
    }
#pragma unroll
    for (int i = 0; i < 4; ++i) {
        int row = row0 + ty * 4 + i;
        if (row >= M) continue;
        float os = rowscale_out ? rowscale_out[row] : 1.0f;
        float4 o;
        float vals[4];
#pragma unroll
        for (int j = 0; j < 4; ++j) {
            float v = acc[i][j] + bias_v[j];
            if (do_relu) v = fmaxf(v, 0.f);
            vals[j] = v * os;
        }
        o.x = vals[0]; o.y = vals[1]; o.z = vals[2]; o.w = vals[3];
        *reinterpret_cast<float4*>(&C[(size_t)row * Nc + col0 + tx * 4]) = o;
        if (C2) *reinterpret_cast<float4*>(&C2[(size_t)row * Nc + col0 + tx * 4]) = o;
    }
}

// out[i][:] = out[i][:] * in_isqrt[i] + bias[:]
template <int DQ>
__global__ void k_finalize(float* __restrict__ out, const float* __restrict__ in_isqrt,
                           const float* __restrict__ bias, int total) {
    int t = blockIdx.x * blockDim.x + threadIdx.x;
    if (t >= total) return;
    int row = t / DQ;
    int c = t - row * DQ;
    float4 v = reinterpret_cast<float4*>(out)[t];
    float4 b = reinterpret_cast<const float4*>(bias)[c];
    float s = in_isqrt[row];
    v.x = v.x * s + b.x;
    v.y = v.y * s + b.y;
    v.z = v.z * s + b.z;
    v.w = v.w * s + b.w;
    reinterpret_cast<float4*>(out)[t] = v;
}

extern "C" void kernel_launch(void* const* d_in, const int* in_sizes, int n_in,
                              void* d_out, int out_size, void* d_ws, size_t ws_size,
                              hipStream_t stream) {
    const float* x  = (const float*)d_in[0];
    const int*   ei = (const int*)d_in[1];
    const float* W1 = (const float*)d_in[2];
    const float* b1 = (const float*)d_in[3];
    const float* W2 = (const float*)d_in[4];
    const float* b2 = (const float*)d_in[5];
    float* out = (float*)d_out;

    const int N = in_sizes[0] / IN_DIM;
    const int E = in_sizes[1] / 2;
    const int* src = ei;
    const int* dst = ei + E;

    // workspace carve-up (256B aligned)
    char* ws = (char*)d_ws;
    size_t off = 0;
    auto alloc = [&](size_t bytes) {
        void* p = ws + off;
        off += (bytes + 255) & ~(size_t)255;
        return p;
    };
    int*   deg_src   = (int*)alloc((size_t)N * sizeof(int));
    int*   deg_dst   = (int*)alloc((size_t)N * sizeof(int));
    float* out_isqrt = (float*)alloc((size_t)N * sizeof(float));
    float* in_isqrt  = (float*)alloc((size_t)N * sizeof(float));
    float* m1 = (float*)alloc((size_t)N * IN_DIM * sizeof(float));   // 25.6 MB
    float* h1 = (float*)alloc((size_t)N * HID_DIM * sizeof(float));  // 51.2 MB
    float* t2 = (float*)alloc((size_t)N * OUT_DIM * sizeof(float));  // 25.6 MB

    const int thr = 256;

    // degrees + normalizers
    k_init_deg<<<DIV_UP(N, thr), thr, 0, stream>>>(deg_src, deg_dst, N);
    k_count_deg<<<DIV_UP(E, thr), thr, 0, stream>>>(src, dst, deg_src, deg_dst, E);
    k_isqrt<<<DIV_UP(N, thr), thr, 0, stream>>>(deg_src, deg_dst, out_isqrt, in_isqrt, N);

    // layer 1: aggregate x (128d) with scale out_isqrt; self-loop via init
    k_scale_init<32><<<DIV_UP(N * 32, thr), thr, 0, stream>>>(x, out_isqrt, m1, N * 32);
    k_scatter<32, true><<<DIV_UP(E * 32, thr), thr, 0, stream>>>(x, m1, src, dst, out_isqrt, E);
    // h1 = relu((in_isqrt ⊙ m1) @ W1 + b1)
    k_gemm<<<dim3(HID_DIM / 64, DIV_UP(N, 64)), 256, 0, stream>>>(
        m1, W1, b1, in_isqrt, nullptr, h1, nullptr, N, IN_DIM, HID_DIM, 1);

    // layer 2: t2 = (h1 @ W2) * out_isqrt  (dual-store: t2 for gather, out as self-loop init)
    k_gemm<<<dim3(OUT_DIM / 64, DIV_UP(N, 64)), 256, 0, stream>>>(
        h1, W2, nullptr, nullptr, out_isqrt, t2, out, N, HID_DIM, OUT_DIM, 0);
    k_scatter<32, false><<<DIV_UP(E * 32, thr), thr, 0, stream>>>(t2, out, src, dst, nullptr, E);
    // out = out * in_isqrt + b2
    k_finalize<32><<<DIV_UP(N * 32, thr), thr, 0, stream>>>(out, in_isqrt, b2, N * 32);
}

// Round 2
// 460.301 us; speedup vs baseline: 6.4101x; 6.4101x over previous
//
#include <hip/hip_runtime.h>
#include <math.h>

// GCN 2-layer: out = A_norm @ relu(A_norm @ x @ W1 + b1) @ W2 + b2
// A_norm = D_dst^{-1/2} (A + I) D_src^{-1/2}
// Structure:
//   - Build CSR (dst-sorted in-edges) once: count -> scan -> fill (int atomics only).
//   - layer1: gather-aggregate x (128d, per-src out_isqrt scale) -> m1;
//             GEMM 128->256 with rowscale_in=in_isqrt, +b1, relu -> h1
//   - layer2: GEMM h1@W2 (256->128) with rowscale_out=out_isqrt -> t2;
//             gather-aggregate t2 -> out, epilogue *in_isqrt + b2 (fused).
// No fp32 atomics anywhere (they were 91% of round-1 runtime).

constexpr int IN_DIM  = 128;
constexpr int HID_DIM = 256;
constexpr int OUT_DIM = 128;

#define DIV_UP(a, b) (((a) + (b) - 1) / (b))

__global__ void k_zero_deg(int* __restrict__ cnt_src, int* __restrict__ cnt_dst, int n) {
    int i = blockIdx.x * blockDim.x + threadIdx.x;
    if (i < n) { cnt_src[i] = 0; cnt_dst[i] = 0; }
}

__global__ void k_count_deg(const int* __restrict__ src, const int* __restrict__ dst,
                            int* __restrict__ cnt_src, int* __restrict__ cnt_dst, int e) {
    int i = blockIdx.x * blockDim.x + threadIdx.x;
    if (i < e) {
        atomicAdd(&cnt_src[src[i]], 1);
        atomicAdd(&cnt_dst[dst[i]], 1);
    }
}

// degree = real count + 1 (self loop)
__global__ void k_isqrt(const int* __restrict__ cnt_src, const int* __restrict__ cnt_dst,
                        float* __restrict__ out_isqrt, float* __restrict__ in_isqrt, int n) {
    int i = blockIdx.x * blockDim.x + threadIdx.x;
    if (i < n) {
        out_isqrt[i] = 1.0f / sqrtf((float)(cnt_src[i] + 1));
        in_isqrt[i]  = 1.0f / sqrtf((float)(cnt_dst[i] + 1));
    }
}

// Single-workgroup exclusive prefix scan of cnt_dst -> row_off (+ cursor copy).
__global__ __launch_bounds__(1024) void k_scan_csr(const int* __restrict__ cnt,
                                                   int* __restrict__ row_off,
                                                   int* __restrict__ cursor, int n) {
    __shared__ int wsum[16];
    __shared__ int carry_s;
    const int tid = threadIdx.x;
    const int lane = tid & 63, wid = tid >> 6;
    if (tid == 0) carry_s = 0;
    for (int base = 0; base < n; base += 1024) {
        __syncthreads();
        int carry = carry_s;
        int i = base + tid;
        int v = (i < n) ? cnt[i] : 0;
        int x = v;
#pragma unroll
        for (int off = 1; off < 64; off <<= 1) {
            int t = __shfl_up(x, off);
            if (lane >= off) x += t;
        }
        if (lane == 63) wsum[wid] = x;
        __syncthreads();
        if (wid == 0) {
            int w = (lane < 16) ? wsum[lane] : 0;
#pragma unroll
            for (int off = 1; off < 16; off <<= 1) {
                int t = __shfl_up(w, off);
                if (lane >= off) w += t;
            }
            if (lane < 16) wsum[lane] = w;
        }
        __syncthreads();
        int wave_off = (wid > 0) ? wsum[wid - 1] : 0;
        int excl = carry + wave_off + x - v;
        if (i < n) { row_off[i] = excl; cursor[i] = excl; }
        __syncthreads();
        if (tid == 0) carry_s = carry + wsum[15];
    }
}

__global__ void k_fill_csr(const int* __restrict__ src, const int* __restrict__ dst,
                           int* __restrict__ cursor, int* __restrict__ csr_src, int e) {
    int i = blockIdx.x * blockDim.x + threadIdx.x;
    if (i < e) {
        int p = atomicAdd(&cursor[dst[i]], 1);
        csr_src[p] = src[i];
    }
}

// One wave per node; lane holds float2 (128 dims). Self-loop included.
// outv[node] = outscale(node) * ( feat[node]*s(node) + sum_e feat[src]*s(src) ) + bias
// s(i) = HAS_SCALE ? scale[i] : 1; outscale = HAS_OUT ? oscale[node] : 1.
template <bool HAS_SCALE, bool HAS_OUT>
__global__ __launch_bounds__(256) void k_gather(
    const float* __restrict__ feat, const int* __restrict__ row_off,
    const int* __restrict__ cnt, const int* __restrict__ csr_src,
    const float* __restrict__ scale, const float* __restrict__ oscale,
    const float* __restrict__ bias, float* __restrict__ outv, int n) {
    const int node = blockIdx.x * (blockDim.x >> 6) + (threadIdx.x >> 6);
    const int lane = threadIdx.x & 63;
    if (node >= n) return;
    const float2* f = reinterpret_cast<const float2*>(feat);

    float2 v = f[(size_t)node * 64 + lane];
    float s = HAS_SCALE ? scale[node] : 1.0f;
    float2 acc = make_float2(v.x * s, v.y * s);

    const int b = row_off[node];
    const int e2 = b + cnt[node];
    int k = b;
    for (; k + 4 <= e2; k += 4) {
        int s0 = csr_src[k], s1 = csr_src[k + 1], s2 = csr_src[k + 2], s3 = csr_src[k + 3];
        float2 v0 = f[(size_t)s0 * 64 + lane];
        float2 v1 = f[(size_t)s1 * 64 + lane];
        float2 v2 = f[(size_t)s2 * 64 + lane];
        float2 v3 = f[(size_t)s3 * 64 + lane];
        if (HAS_SCALE) {
            float c0 = scale[s0], c1 = scale[s1], c2 = scale[s2], c3 = scale[s3];
            acc.x += v0.x * c0 + v1.x * c1 + v2.x * c2 + v3.x * c3;
            acc.y += v0.y * c0 + v1.y * c1 + v2.y * c2 + v3.y * c3;
        } else {
            acc.x += v0.x + v1.x + v2.x + v3.x;
            acc.y += v0.y + v1.y + v2.y + v3.y;
        }
    }
    for (; k < e2; ++k) {
        int si = csr_src[k];
        float2 vv = f[(size_t)si * 64 + lane];
        float c = HAS_SCALE ? scale[si] : 1.0f;
        acc.x += vv.x * c;
        acc.y += vv.y * c;
    }

    if (HAS_OUT) {
        float os = oscale[node];
        acc.x *= os; acc.y *= os;
    }
    if (bias) {
        float2 bb = reinterpret_cast<const float2*>(bias)[lane];
        acc.x += bb.x; acc.y += bb.y;
    }
    reinterpret_cast<float2*>(outv)[(size_t)node * 64 + lane] = acc;
}

// C = epilogue( (rowscale_in ⊙ A) @ B ), A: MxK row-major, B: KxNc row-major.
__global__ __launch_bounds__(256) void k_gemm(
    const float* __restrict__ A, const float* __restrict__ B,
    const float* __restrict__ bias, const float* __restrict__ rowscale_in,
    const float* __restrict__ rowscale_out,
    float* __restrict__ C,
    int M, int K, int Nc, int do_relu) {
    __shared__ float As[32][64];  // k-major
    __shared__ float Bs[32][64];

    const int tid = threadIdx.x;
    const int tx = tid & 15;   // -> 4 cols
    const int ty = tid >> 4;   // -> 4 rows
    const int row0 = blockIdx.y * 64;
    const int col0 = blockIdx.x * 64;

    float acc[4][4] = {};

    for (int kb = 0; kb < K; kb += 32) {
#pragma unroll
        for (int l = 0; l < 2; ++l) {
            int li = tid + l * 256;
            int r = li >> 3;
            int kq = li & 7;
            int row = row0 + r;
            float4 v = make_float4(0.f, 0.f, 0.f, 0.f);
            if (row < M) {
                v = *reinterpret_cast<const float4*>(&A[(size_t)row * K + kb + kq * 4]);
                if (rowscale_in) {
                    float s = rowscale_in[row];
                    v.x *= s; v.y *= s; v.z *= s; v.w *= s;
                }
            }
            As[kq * 4 + 0][r] = v.x;
            As[kq * 4 + 1][r] = v.y;
            As[kq * 4 + 2][r] = v.z;
            As[kq * 4 + 3][r] = v.w;
        }
#pragma unroll
        for (int l = 0; l < 2; ++l) {
            int li = tid + l * 256;
            int c4 = li & 15;
            int kk = li >> 4;
            float4 v = *reinterpret_cast<const float4*>(&B[(size_t)(kb + kk) * Nc + col0 + c4 * 4]);
            *reinterpret_cast<float4*>(&Bs[kk][c4 * 4]) = v;
        }
        __syncthreads();
#pragma unroll
        for (int k = 0; k < 32; ++k) {
            float4 av = *reinterpret_cast<float4*>(&As[k][ty * 4]);
            float4 bv = *reinterpret_cast<float4*>(&Bs[k][tx * 4]);
            float a_[4] = {av.x, av.y, av.z, av.w};
            float b_[4] = {bv.x, bv.y, bv.z, bv.w};
#pragma unroll
            for (int i = 0; i < 4; ++i)
#pragma unroll
                for (int j = 0; j < 4; ++j)
                    acc[i][j] += a_[i] * b_[j];
        }
        __syncthreads();
    }

    float bias_v[4] = {0.f, 0.f, 0.f, 0.f};
    if (bias) {
#pragma unroll
        for (int j = 0; j < 4; ++j) bias_v[j] = bias[col0 + tx * 4 + j];
    }
#pragma unroll
    for (int i = 0; i < 4; ++i) {
        int row = row0 + ty * 4 + i;
        if (row >= M) continue;
        float os = rowscale_out ? rowscale_out[row] : 1.0f;
        float4 o;
#pragma unroll
        for (int j = 0; j < 4; ++j) {
            float v = acc[i][j] + bias_v[j];
            if (do_relu) v = fmaxf(v, 0.f);
            ((float*)&o)[j] = v * os;
        }
        *reinterpret_cast<float4*>(&C[(size_t)row * Nc + col0 + tx * 4]) = o;
    }
}

extern "C" void kernel_launch(void* const* d_in, const int* in_sizes, int n_in,
                              void* d_out, int out_size, void* d_ws, size_t ws_size,
                              hipStream_t stream) {
    const float* x  = (const float*)d_in[0];
    const int*   ei = (const int*)d_in[1];
    const float* W1 = (const float*)d_in[2];
    const float* b1 = (const float*)d_in[3];
    const float* W2 = (const float*)d_in[4];
    const float* b2 = (const float*)d_in[5];
    float* out = (float*)d_out;

    const int N = in_sizes[0] / IN_DIM;
    const int E = in_sizes[1] / 2;
    const int* src = ei;
    const int* dst = ei + E;

    char* ws = (char*)d_ws;
    size_t off = 0;
    auto alloc = [&](size_t bytes) {
        void* p = ws + off;
        off += (bytes + 255) & ~(size_t)255;
        return p;
    };
    int*   cnt_src   = (int*)alloc((size_t)N * sizeof(int));
    int*   cnt_dst   = (int*)alloc((size_t)N * sizeof(int));
    float* out_isqrt = (float*)alloc((size_t)N * sizeof(float));
    float* in_isqrt  = (float*)alloc((size_t)N * sizeof(float));
    int*   row_off   = (int*)alloc((size_t)N * sizeof(int));
    int*   cursor    = (int*)alloc((size_t)N * sizeof(int));
    int*   csr_src   = (int*)alloc((size_t)E * sizeof(int));            // 3.2 MB
    float* m1 = (float*)alloc((size_t)N * IN_DIM * sizeof(float));      // 25.6 MB
    float* h1 = (float*)alloc((size_t)N * HID_DIM * sizeof(float));     // 51.2 MB
    float* t2 = (float*)alloc((size_t)N * OUT_DIM * sizeof(float));     // 25.6 MB

    const int thr = 256;

    // degrees + normalizers + CSR
    k_zero_deg<<<DIV_UP(N, thr), thr, 0, stream>>>(cnt_src, cnt_dst, N);
    k_count_deg<<<DIV_UP(E, thr), thr, 0, stream>>>(src, dst, cnt_src, cnt_dst, E);
    k_isqrt<<<DIV_UP(N, thr), thr, 0, stream>>>(cnt_src, cnt_dst, out_isqrt, in_isqrt, N);
    k_scan_csr<<<1, 1024, 0, stream>>>(cnt_dst, row_off, cursor, N);
    k_fill_csr<<<DIV_UP(E, thr), thr, 0, stream>>>(src, dst, cursor, csr_src, E);

    // layer 1: m1 = (A+I) (out_isqrt ⊙ x); h1 = relu((in_isqrt ⊙ m1)@W1 + b1)
    k_gather<true, false><<<DIV_UP(N, 4), 256, 0, stream>>>(
        x, row_off, cnt_dst, csr_src, out_isqrt, nullptr, nullptr, m1, N);
    k_gemm<<<dim3(HID_DIM / 64, DIV_UP(N, 64)), 256, 0, stream>>>(
        m1, W1, b1, in_isqrt, nullptr, h1, N, IN_DIM, HID_DIM, 1);

    // layer 2: t2 = (h1@W2) ⊙ out_isqrt; out = in_isqrt ⊙ ((A+I) t2) + b2
    k_gemm<<<dim3(OUT_DIM / 64, DIV_UP(N, 64)), 256, 0, stream>>>(
        h1, W2, nullptr, nullptr, out_isqrt, t2, N, HID_DIM, OUT_DIM, 0);
    k_gather<false, true><<<DIV_UP(N, 4), 256, 0, stream>>>(
        t2, row_off, cnt_dst, csr_src, nullptr, in_isqrt, b2, out, N);
}

// Round 3
// 398.737 us; speedup vs baseline: 7.3999x; 1.1544x over previous
//
#include <hip/hip_runtime.h>
#include <math.h>

// GCN 2-layer: out = A_norm @ relu(A_norm @ x @ W1 + b1) @ W2 + b2
// A_norm = D_dst^{-1/2} (A + I) D_src^{-1/2}
// Structure:
//   - CSR build (dst-sorted): count (int atomics) -> multi-block scan -> fill.
//   - layer1: gather-aggregate x (128d, per-src out_isqrt) -> m1;
//             MFMA GEMM 128->256 (rowscale_in=in_isqrt, +b1, relu) -> h1
//   - layer2: MFMA GEMM h1@W2 (256->128, rowscale_out=out_isqrt) -> t2;
//             gather-aggregate t2 -> out (fused *in_isqrt + b2).
// GEMMs use split-bf16 (Dekker hi/lo, 3 MFMA products) for ~fp32 precision on
// the bf16 matrix pipe; W pre-packed per launch into MFMA fragment order.

constexpr int IN_DIM  = 128;
constexpr int HID_DIM = 256;
constexpr int OUT_DIM = 128;

#define DIV_UP(a, b) (((a) + (b) - 1) / (b))

typedef __attribute__((ext_vector_type(8))) short bf16x8;
typedef __attribute__((ext_vector_type(4))) float f32x4;

__global__ void k_zero2(int* __restrict__ a, int* __restrict__ b, int n) {
    int i = blockIdx.x * blockDim.x + threadIdx.x;
    if (i < n) { a[i] = 0; b[i] = 0; }
}

// 4 edges/thread for atomic ILP
__global__ void k_count_deg4(const int* __restrict__ src, const int* __restrict__ dst,
                             int* __restrict__ cs, int* __restrict__ cd, int e) {
    int i = (blockIdx.x * blockDim.x + threadIdx.x) * 4;
    if (i + 3 < e) {
        int4 s = *reinterpret_cast<const int4*>(src + i);
        int4 d = *reinterpret_cast<const int4*>(dst + i);
        atomicAdd(&cs[s.x], 1); atomicAdd(&cs[s.y], 1);
        atomicAdd(&cs[s.z], 1); atomicAdd(&cs[s.w], 1);
        atomicAdd(&cd[d.x], 1); atomicAdd(&cd[d.y], 1);
        atomicAdd(&cd[d.z], 1); atomicAdd(&cd[d.w], 1);
    } else {
        for (int k = i; k < e; ++k) { atomicAdd(&cs[src[k]], 1); atomicAdd(&cd[dst[k]], 1); }
    }
}

__global__ void k_isqrt(const int* __restrict__ cs, const int* __restrict__ cd,
                        float* __restrict__ out_isqrt, float* __restrict__ in_isqrt, int n) {
    int i = blockIdx.x * blockDim.x + threadIdx.x;
    if (i < n) {
        out_isqrt[i] = 1.0f / sqrtf((float)(cs[i] + 1));
        in_isqrt[i]  = 1.0f / sqrtf((float)(cd[i] + 1));
    }
}

// ---- multi-block exclusive scan (1024 elems/block, 256 thr x 4) ----
__global__ __launch_bounds__(256) void k_scan_local(const int* __restrict__ cnt,
                                                    int* __restrict__ local,
                                                    int* __restrict__ chunk_sums, int n) {
    __shared__ int wsum[4];
    const int tid = threadIdx.x, lane = tid & 63, wid = tid >> 6;
    const int i = blockIdx.x * 1024 + tid * 4;
    int4 v = make_int4(0, 0, 0, 0);
    if (i + 3 < n) {
        v = *reinterpret_cast<const int4*>(cnt + i);
    } else if (i < n) {
        v.x = cnt[i];
        if (i + 1 < n) v.y = cnt[i + 1];
        if (i + 2 < n) v.z = cnt[i + 2];
    }
    int s = v.x + v.y + v.z + v.w;
    int x = s;
#pragma unroll
    for (int off = 1; off < 64; off <<= 1) { int t = __shfl_up(x, off); if (lane >= off) x += t; }
    if (lane == 63) wsum[wid] = x;
    __syncthreads();
    int wo = 0;
    for (int w = 0; w < wid; ++w) wo += wsum[w];
    int excl = wo + x - s;
    if (i < n) {
        int4 o;
        o.x = excl; o.y = excl + v.x; o.z = o.y + v.y; o.w = o.z + v.z;
        if (i + 3 < n) *reinterpret_cast<int4*>(local + i) = o;
        else { local[i] = o.x; if (i + 1 < n) local[i + 1] = o.y; if (i + 2 < n) local[i + 2] = o.z; }
    }
    if (tid == 255) chunk_sums[blockIdx.x] = wo + x;
}

__global__ void k_scan_chunks(int* __restrict__ chunk_sums, int nc) {  // nc <= 64, 1 block x 64
    int l = threadIdx.x;
    int v = (l < nc) ? chunk_sums[l] : 0;
    int x = v;
#pragma unroll
    for (int off = 1; off < 64; off <<= 1) { int t = __shfl_up(x, off); if (l >= off) x += t; }
    if (l < nc) chunk_sums[l] = x - v;
}

__global__ void k_scan_apply(const int* __restrict__ local, const int* __restrict__ chunk_sums,
                             int* __restrict__ row_off, int* __restrict__ cursor, int n) {
    int i = (blockIdx.x * blockDim.x + threadIdx.x) * 4;
    if (i >= n) return;
    int add = chunk_sums[i >> 10];
    if (i + 3 < n) {
        int4 v = *reinterpret_cast<const int4*>(local + i);
        v.x += add; v.y += add; v.z += add; v.w += add;
        *reinterpret_cast<int4*>(row_off + i) = v;
        *reinterpret_cast<int4*>(cursor + i) = v;
    } else {
        for (int k = i; k < n; ++k) { int t = local[k] + add; row_off[k] = t; cursor[k] = t; }
    }
}

__global__ void k_fill_csr4(const int* __restrict__ src, const int* __restrict__ dst,
                            int* __restrict__ cursor, int* __restrict__ csr_src, int e) {
    int i = (blockIdx.x * blockDim.x + threadIdx.x) * 4;
    if (i + 3 < e) {
        int4 s = *reinterpret_cast<const int4*>(src + i);
        int4 d = *reinterpret_cast<const int4*>(dst + i);
        int p0 = atomicAdd(&cursor[d.x], 1);
        int p1 = atomicAdd(&cursor[d.y], 1);
        int p2 = atomicAdd(&cursor[d.z], 1);
        int p3 = atomicAdd(&cursor[d.w], 1);
        csr_src[p0] = s.x; csr_src[p1] = s.y; csr_src[p2] = s.z; csr_src[p3] = s.w;
    } else {
        for (int k = i; k < e; ++k) { int p = atomicAdd(&cursor[dst[k]], 1); csr_src[p] = src[k]; }
    }
}

// One wave per node; lane holds float2 (128 dims). Self-loop included.
template <bool HAS_SCALE, bool HAS_OUT>
__global__ __launch_bounds__(256) void k_gather(
    const float* __restrict__ feat, const int* __restrict__ row_off,
    const int* __restrict__ cnt, const int* __restrict__ csr_src,
    const float* __restrict__ scale, const float* __restrict__ oscale,
    const float* __restrict__ bias, float* __restrict__ outv, int n) {
    const int node = blockIdx.x * (blockDim.x >> 6) + (threadIdx.x >> 6);
    const int lane = threadIdx.x & 63;
    if (node >= n) return;
    const float2* f = reinterpret_cast<const float2*>(feat);

    float2 v = f[(size_t)node * 64 + lane];
    float s = HAS_SCALE ? scale[node] : 1.0f;
    float2 acc = make_float2(v.x * s, v.y * s);

    const int b = row_off[node];
    const int e2 = b + cnt[node];
    int k = b;
    for (; k + 4 <= e2; k += 4) {
        int s0 = csr_src[k], s1 = csr_src[k + 1], s2 = csr_src[k + 2], s3 = csr_src[k + 3];
        float2 v0 = f[(size_t)s0 * 64 + lane];
        float2 v1 = f[(size_t)s1 * 64 + lane];
        float2 v2 = f[(size_t)s2 * 64 + lane];
        float2 v3 = f[(size_t)s3 * 64 + lane];
        if (HAS_SCALE) {
            float c0 = scale[s0], c1 = scale[s1], c2 = scale[s2], c3 = scale[s3];
            acc.x += v0.x * c0 + v1.x * c1 + v2.x * c2 + v3.x * c3;
            acc.y += v0.y * c0 + v1.y * c1 + v2.y * c2 + v3.y * c3;
        } else {
            acc.x += v0.x + v1.x + v2.x + v3.x;
            acc.y += v0.y + v1.y + v2.y + v3.y;
        }
    }
    for (; k < e2; ++k) {
        int si = csr_src[k];
        float2 vv = f[(size_t)si * 64 + lane];
        float c = HAS_SCALE ? scale[si] : 1.0f;
        acc.x += vv.x * c;
        acc.y += vv.y * c;
    }

    if (HAS_OUT) { float os = oscale[node]; acc.x *= os; acc.y *= os; }
    if (bias) {
        float2 bb = reinterpret_cast<const float2*>(bias)[lane];
        acc.x += bb.x; acc.y += bb.y;
    }
    reinterpret_cast<float2*>(outv)[(size_t)node * 64 + lane] = acc;
}

// Pack W[K][N] fp32 -> hi/lo bf16 in MFMA-B fragment order:
// idx = ((nt*KT + kt)*64 + lane)*8 + j ; k = kt*32 + (lane>>4)*8 + j ; col = nt*16 + (lane&15)
__global__ void k_pack_w(const float* __restrict__ W, short* __restrict__ hi,
                         short* __restrict__ lo, int KT, int N) {
    int idx = blockIdx.x * blockDim.x + threadIdx.x;
    int total = KT * 32 * N;
    if (idx >= total) return;
    int j = idx & 7;
    int l = (idx >> 3) & 63;
    int rest = idx >> 9;
    int kt = rest % KT;
    int nt = rest / KT;
    int k = kt * 32 + ((l >> 4) << 3) + j;
    int col = nt * 16 + (l & 15);
    float w = W[(size_t)k * N + col];
    unsigned u = __builtin_bit_cast(unsigned, w);
    hi[idx] = (short)(u >> 16);
    float hif = __builtin_bit_cast(float, u & 0xFFFF0000u);
    lo[idx] = (short)(__builtin_bit_cast(unsigned, w - hif) >> 16);
}

// C[M x Nc] = epi( (rs_in ⊙ A[M x K]) @ W ), split-bf16 MFMA (hi*hi + lo*hi + hi*lo).
// Block: 256 thr = 4 waves; wave does 16 rows x 128 cols (8 col-tiles of 16x16x32 MFMA).
// No LDS, no barriers. A frags loaded straight from global (32B/lane contiguous).
template <int KT, bool HAS_RSIN, bool HAS_BIAS, bool RELU, bool HAS_RSOUT>
__global__ __launch_bounds__(256) void k_gemm_mfma(
    const float* __restrict__ A, const short* __restrict__ Bp_hi,
    const short* __restrict__ Bp_lo, const float* __restrict__ bias,
    const float* __restrict__ rs_in, const float* __restrict__ rs_out,
    float* __restrict__ C, int M, int Nc) {
    const int K = KT * 32;
    const int lane = threadIdx.x & 63;
    const int wave = threadIdx.x >> 6;
    const int row0 = blockIdx.y * 64 + wave * 16;
    const int colt0 = blockIdx.x * 8;  // global col-tile base (128 cols)

    int arow = row0 + (lane & 15);
    int ar = arow < M ? arow : M - 1;
    const int koff = (lane >> 4) << 3;
    const float rs = HAS_RSIN ? rs_in[ar] : 1.0f;

    f32x4 acc[8];
#pragma unroll
    for (int t = 0; t < 8; ++t) acc[t] = (f32x4){0.f, 0.f, 0.f, 0.f};

    const bf16x8* bh = reinterpret_cast<const bf16x8*>(Bp_hi);
    const bf16x8* bl = reinterpret_cast<const bf16x8*>(Bp_lo);

#pragma unroll
    for (int kt = 0; kt < KT; ++kt) {
        const float* ap = A + (size_t)ar * K + kt * 32 + koff;
        float av[8];
        *reinterpret_cast<float4*>(&av[0]) = *reinterpret_cast<const float4*>(ap);
        *reinterpret_cast<float4*>(&av[4]) = *reinterpret_cast<const float4*>(ap + 4);
        bf16x8 a_hi, a_lo;
#pragma unroll
        for (int j = 0; j < 8; ++j) {
            float a = av[j] * rs;
            unsigned u = __builtin_bit_cast(unsigned, a);
            a_hi[j] = (short)(u >> 16);
            float hif = __builtin_bit_cast(float, u & 0xFFFF0000u);
            a_lo[j] = (short)(__builtin_bit_cast(unsigned, a - hif) >> 16);
        }
#pragma unroll
        for (int ct = 0; ct < 8; ++ct) {
            int bidx = (colt0 + ct) * KT + kt;
            bf16x8 bhv = bh[bidx * 64 + lane];
            bf16x8 blv = bl[bidx * 64 + lane];
            acc[ct] = __builtin_amdgcn_mfma_f32_16x16x32_bf16(a_hi, bhv, acc[ct], 0, 0, 0);
            acc[ct] = __builtin_amdgcn_mfma_f32_16x16x32_bf16(a_lo, bhv, acc[ct], 0, 0, 0);
            acc[ct] = __builtin_amdgcn_mfma_f32_16x16x32_bf16(a_hi, blv, acc[ct], 0, 0, 0);
        }
    }

    // epilogue: C row = row0 + (lane>>4)*4 + j, col = 16*tile + (lane&15)
    const int crow0 = row0 + ((lane >> 4) << 2);
    float rso[4];
#pragma unroll
    for (int j = 0; j < 4; ++j)
        rso[j] = HAS_RSOUT ? ((crow0 + j < M) ? rs_out[crow0 + j] : 0.f) : 1.0f;

#pragma unroll
    for (int ct = 0; ct < 8; ++ct) {
        int col = (colt0 + ct) * 16 + (lane & 15);
        float bv = HAS_BIAS ? bias[col] : 0.f;
#pragma unroll
        for (int j = 0; j < 4; ++j) {
            int row = crow0 + j;
            if (row >= M) continue;
            float v = acc[ct][j] + bv;
            if (RELU) v = fmaxf(v, 0.f);
            v *= rso[j];
            C[(size_t)row * Nc + col] = v;
        }
    }
}

extern "C" void kernel_launch(void* const* d_in, const int* in_sizes, int n_in,
                              void* d_out, int out_size, void* d_ws, size_t ws_size,
                              hipStream_t stream) {
    const float* x  = (const float*)d_in[0];
    const int*   ei = (const int*)d_in[1];
    const float* W1 = (const float*)d_in[2];
    const float* b1 = (const float*)d_in[3];
    const float* W2 = (const float*)d_in[4];
    const float* b2 = (const float*)d_in[5];
    float* out = (float*)d_out;

    const int N = in_sizes[0] / IN_DIM;
    const int E = in_sizes[1] / 2;
    const int* src = ei;
    const int* dst = ei + E;

    char* ws = (char*)d_ws;
    size_t off = 0;
    auto alloc = [&](size_t bytes) {
        void* p = ws + off;
        off += (bytes + 255) & ~(size_t)255;
        return p;
    };
    int*   cnt_src   = (int*)alloc((size_t)N * sizeof(int));
    int*   cnt_dst   = (int*)alloc((size_t)N * sizeof(int));
    float* out_isqrt = (float*)alloc((size_t)N * sizeof(float));
    float* in_isqrt  = (float*)alloc((size_t)N * sizeof(float));
    int*   row_off   = (int*)alloc((size_t)N * sizeof(int));
    int*   cursor    = (int*)alloc((size_t)N * sizeof(int));
    int*   scan_loc  = (int*)alloc((size_t)N * sizeof(int));
    int*   chunk_sum = (int*)alloc(64 * sizeof(int));
    int*   csr_src   = (int*)alloc((size_t)E * sizeof(int));
    short* W1p_hi    = (short*)alloc((size_t)IN_DIM * HID_DIM * sizeof(short));
    short* W1p_lo    = (short*)alloc((size_t)IN_DIM * HID_DIM * sizeof(short));
    short* W2p_hi    = (short*)alloc((size_t)HID_DIM * OUT_DIM * sizeof(short));
    short* W2p_lo    = (short*)alloc((size_t)HID_DIM * OUT_DIM * sizeof(short));
    float* m1 = (float*)alloc((size_t)N * IN_DIM * sizeof(float));
    float* h1 = (float*)alloc((size_t)N * HID_DIM * sizeof(float));
    float* t2 = (float*)alloc((size_t)N * OUT_DIM * sizeof(float));

    const int thr = 256;
    const int nchunks = DIV_UP(N, 1024);

    // degrees + normalizers + CSR
    k_zero2<<<DIV_UP(N, thr), thr, 0, stream>>>(cnt_src, cnt_dst, N);
    k_count_deg4<<<DIV_UP(E / 4, thr), thr, 0, stream>>>(src, dst, cnt_src, cnt_dst, E);
    k_isqrt<<<DIV_UP(N, thr), thr, 0, stream>>>(cnt_src, cnt_dst, out_isqrt, in_isqrt, N);
    k_scan_local<<<nchunks, thr, 0, stream>>>(cnt_dst, scan_loc, chunk_sum, N);
    k_scan_chunks<<<1, 64, 0, stream>>>(chunk_sum, nchunks);
    k_scan_apply<<<DIV_UP(N, 4 * thr), thr, 0, stream>>>(scan_loc, chunk_sum, row_off, cursor, N);
    k_fill_csr4<<<DIV_UP(E / 4, thr), thr, 0, stream>>>(src, dst, cursor, csr_src, E);

    // weight packing (fragment-ordered bf16 hi/lo)
    k_pack_w<<<DIV_UP(IN_DIM * HID_DIM, thr), thr, 0, stream>>>(W1, W1p_hi, W1p_lo, IN_DIM / 32, HID_DIM);
    k_pack_w<<<DIV_UP(HID_DIM * OUT_DIM, thr), thr, 0, stream>>>(W2, W2p_hi, W2p_lo, HID_DIM / 32, OUT_DIM);

    // layer 1: m1 = (A+I)(out_isqrt ⊙ x); h1 = relu((in_isqrt ⊙ m1)@W1 + b1)
    k_gather<true, false><<<DIV_UP(N, 4), 256, 0, stream>>>(
        x, row_off, cnt_dst, csr_src, out_isqrt, nullptr, nullptr, m1, N);
    k_gemm_mfma<IN_DIM / 32, true, true, true, false>
        <<<dim3(HID_DIM / 128, DIV_UP(N, 64)), 256, 0, stream>>>(
            m1, W1p_hi, W1p_lo, b1, in_isqrt, nullptr, h1, N, HID_DIM);

    // layer 2: t2 = (h1@W2) ⊙ out_isqrt; out = in_isqrt ⊙ ((A+I) t2) + b2
    k_gemm_mfma<HID_DIM / 32, false, false, false, true>
        <<<dim3(OUT_DIM / 128, DIV_UP(N, 64)), 256, 0, stream>>>(
            h1, W2p_hi, W2p_lo, nullptr, nullptr, out_isqrt, t2, N, OUT_DIM);
    k_gather<false, true><<<DIV_UP(N, 4), 256, 0, stream>>>(
        t2, row_off, cnt_dst, csr_src, nullptr, in_isqrt, b2, out, N);
}

// Round 4
// 333.575 us; speedup vs baseline: 8.8454x; 1.1953x over previous
//
#include <hip/hip_runtime.h>
#include <math.h>

// GCN 2-layer: out = A_norm @ relu(A_norm @ x @ W1 + b1) @ W2 + b2
// A_norm = D_dst^{-1/2} (A + I) D_src^{-1/2}
// Structure:
//   - Degree histograms via LDS privatization (NO global atomics; round-3 top
//     dispatch was atomic-throughput-bound at 23G atomics/s).
//   - Fused reduce: partial-sum -> cnt_dst, out_isqrt, in_isqrt, local scan.
//   - CSR fill (returning int atomics), then gather-based aggregation.
//   - GEMMs: split-bf16 MFMA (Dekker hi/lo, 3 products), W pre-packed.

constexpr int IN_DIM  = 128;
constexpr int HID_DIM = 256;
constexpr int OUT_DIM = 128;

constexpr int HALF_BINS = 25600;          // node-range half (25600*2 >= N), % 1024 == 0
constexpr int HWORDS    = HALF_BINS / 2;  // packed ushort words
constexpr int HIST_G    = 64;             // blocks per (array, half)

#define DIV_UP(a, b) (((a) + (b) - 1) / (b))

typedef __attribute__((ext_vector_type(8))) short bf16x8;
typedef __attribute__((ext_vector_type(4))) float f32x4;

// ---- privatized degree histogram: grid (HIST_G, 4); y = half*2 + arr ----
__global__ __launch_bounds__(256) void k_hist(const int* __restrict__ ei, int E,
                                              unsigned* __restrict__ partials) {
    __shared__ unsigned h32[HWORDS];  // 51200 B, packed 2x ushort
    const int tid = threadIdx.x;
    const int g = blockIdx.x;
    const int arr = blockIdx.y & 1, half = blockIdx.y >> 1;
    const int lo = half * HALF_BINS;
    const int* edges = ei + (size_t)arr * E;

    for (int i = tid; i < HWORDS; i += 256) h32[i] = 0;
    __syncthreads();

    const int chunk = DIV_UP(E, HIST_G);
    const int beg = g * chunk;
    const int end = min(beg + chunk, E);
    if ((beg & 3) == 0) {
        for (int base = beg + tid * 4; base < end; base += 256 * 4) {
            if (base + 3 < end) {
                int4 v = *reinterpret_cast<const int4*>(edges + base);
                int r;
                r = v.x - lo; if ((unsigned)r < HALF_BINS) atomicAdd(&h32[r >> 1], 1u << ((r & 1) << 4));
                r = v.y - lo; if ((unsigned)r < HALF_BINS) atomicAdd(&h32[r >> 1], 1u << ((r & 1) << 4));
                r = v.z - lo; if ((unsigned)r < HALF_BINS) atomicAdd(&h32[r >> 1], 1u << ((r & 1) << 4));
                r = v.w - lo; if ((unsigned)r < HALF_BINS) atomicAdd(&h32[r >> 1], 1u << ((r & 1) << 4));
            } else {
                for (int k = base; k < end; ++k) {
                    int r = edges[k] - lo;
                    if ((unsigned)r < HALF_BINS) atomicAdd(&h32[r >> 1], 1u << ((r & 1) << 4));
                }
            }
        }
    } else {
        for (int k = beg + tid; k < end; k += 256) {
            int r = edges[k] - lo;
            if ((unsigned)r < HALF_BINS) atomicAdd(&h32[r >> 1], 1u << ((r & 1) << 4));
        }
    }
    __syncthreads();

    unsigned* outp = partials + (size_t)(blockIdx.y * HIST_G + g) * HWORDS;
    for (int i = tid; i < HWORDS; i += 256) outp[i] = h32[i];
}

// ---- fused reduce + normalizers + local scan. Block b: nodes [b*1024,(b+1)*1024) ----
__global__ __launch_bounds__(256) void k_reduce_scan(
    const unsigned* __restrict__ partials,
    int* __restrict__ cnt_dst, float* __restrict__ out_isqrt, float* __restrict__ in_isqrt,
    int* __restrict__ scan_loc, int* __restrict__ chunk_sum, int n) {
    __shared__ int wsum[4];
    const int tid = threadIdx.x, lane = tid & 63, wid = tid >> 6;
    const int bnode = blockIdx.x * 1024;
    const int half = (bnode >= HALF_BINS) ? 1 : 0;  // HALF_BINS % 1024 == 0, no straddle
    const int w0 = ((bnode - half * HALF_BINS) >> 1) + tid * 2;

    const unsigned* ps = partials + (size_t)(2 * half + 0) * HIST_G * HWORDS;
    const unsigned* pd = partials + (size_t)(2 * half + 1) * HIST_G * HWORDS;

    int s0 = 0, s1 = 0, s2 = 0, s3 = 0;
    int d0 = 0, d1 = 0, d2 = 0, d3 = 0;
#pragma unroll 4
    for (int g = 0; g < HIST_G; ++g) {
        unsigned a = ps[(size_t)g * HWORDS + w0];
        unsigned b = ps[(size_t)g * HWORDS + w0 + 1];
        unsigned c = pd[(size_t)g * HWORDS + w0];
        unsigned d = pd[(size_t)g * HWORDS + w0 + 1];
        s0 += a & 0xFFFF; s1 += a >> 16; s2 += b & 0xFFFF; s3 += b >> 16;
        d0 += c & 0xFFFF; d1 += c >> 16; d2 += d & 0xFFFF; d3 += d >> 16;
    }

    const int n0 = bnode + tid * 4;
    int sc[4] = {s0, s1, s2, s3};
    int dc[4] = {d0, d1, d2, d3};
#pragma unroll
    for (int j = 0; j < 4; ++j) {
        int node = n0 + j;
        if (node < n) {
            cnt_dst[node] = dc[j];
            out_isqrt[node] = rsqrtf((float)(sc[j] + 1));
            in_isqrt[node]  = rsqrtf((float)(dc[j] + 1));
        } else {
            dc[j] = 0;
        }
    }

    // local exclusive scan of dc over the block's 1024 values
    int s = dc[0] + dc[1] + dc[2] + dc[3];
    int x = s;
#pragma unroll
    for (int off = 1; off < 64; off <<= 1) { int t = __shfl_up(x, off); if (lane >= off) x += t; }
    if (lane == 63) wsum[wid] = x;
    __syncthreads();
    int wo = 0;
    for (int w = 0; w < wid; ++w) wo += wsum[w];
    int excl = wo + x - s;
    int run = excl;
#pragma unroll
    for (int j = 0; j < 4; ++j) {
        int node = n0 + j;
        if (node < n) scan_loc[node] = run;
        run += dc[j];
    }
    if (tid == 255) chunk_sum[blockIdx.x] = wo + x;
}

__global__ void k_scan_chunks(int* __restrict__ chunk_sums, int nc) {  // nc <= 64
    int l = threadIdx.x;
    int v = (l < nc) ? chunk_sums[l] : 0;
    int x = v;
#pragma unroll
    for (int off = 1; off < 64; off <<= 1) { int t = __shfl_up(x, off); if (l >= off) x += t; }
    if (l < nc) chunk_sums[l] = x - v;
}

__global__ void k_scan_apply(const int* __restrict__ local, const int* __restrict__ chunk_sums,
                             int* __restrict__ row_off, int* __restrict__ cursor, int n) {
    int i = (blockIdx.x * blockDim.x + threadIdx.x) * 4;
    if (i >= n) return;
    int add = chunk_sums[i >> 10];
    if (i + 3 < n) {
        int4 v = *reinterpret_cast<const int4*>(local + i);
        v.x += add; v.y += add; v.z += add; v.w += add;
        *reinterpret_cast<int4*>(row_off + i) = v;
        *reinterpret_cast<int4*>(cursor + i) = v;
    } else {
        for (int k = i; k < n; ++k) { int t = local[k] + add; row_off[k] = t; cursor[k] = t; }
    }
}

__global__ void k_fill_csr4(const int* __restrict__ src, const int* __restrict__ dst,
                            int* __restrict__ cursor, int* __restrict__ csr_src, int e) {
    int i = (blockIdx.x * blockDim.x + threadIdx.x) * 4;
    if (i + 3 < e) {
        int4 s = *reinterpret_cast<const int4*>(src + i);
        int4 d = *reinterpret_cast<const int4*>(dst + i);
        int p0 = atomicAdd(&cursor[d.x], 1);
        int p1 = atomicAdd(&cursor[d.y], 1);
        int p2 = atomicAdd(&cursor[d.z], 1);
        int p3 = atomicAdd(&cursor[d.w], 1);
        csr_src[p0] = s.x; csr_src[p1] = s.y; csr_src[p2] = s.z; csr_src[p3] = s.w;
    } else {
        for (int k = i; k < e; ++k) { int p = atomicAdd(&cursor[dst[k]], 1); csr_src[p] = src[k]; }
    }
}

// One wave per node; lane holds float2 (128 dims). Self-loop included.
template <bool HAS_SCALE, bool HAS_OUT>
__global__ __launch_bounds__(256) void k_gather(
    const float* __restrict__ feat, const int* __restrict__ row_off,
    const int* __restrict__ cnt, const int* __restrict__ csr_src,
    const float* __restrict__ scale, const float* __restrict__ oscale,
    const float* __restrict__ bias, float* __restrict__ outv, int n) {
    const int node = blockIdx.x * (blockDim.x >> 6) + (threadIdx.x >> 6);
    const int lane = threadIdx.x & 63;
    if (node >= n) return;
    const float2* f = reinterpret_cast<const float2*>(feat);

    float2 v = f[(size_t)node * 64 + lane];
    float s = HAS_SCALE ? scale[node] : 1.0f;
    float2 acc = make_float2(v.x * s, v.y * s);

    const int b = row_off[node];
    const int e2 = b + cnt[node];
    int k = b;
    for (; k + 4 <= e2; k += 4) {
        int s0 = csr_src[k], s1 = csr_src[k + 1], s2 = csr_src[k + 2], s3 = csr_src[k + 3];
        float2 v0 = f[(size_t)s0 * 64 + lane];
        float2 v1 = f[(size_t)s1 * 64 + lane];
        float2 v2 = f[(size_t)s2 * 64 + lane];
        float2 v3 = f[(size_t)s3 * 64 + lane];
        if (HAS_SCALE) {
            float c0 = scale[s0], c1 = scale[s1], c2 = scale[s2], c3 = scale[s3];
            acc.x += v0.x * c0 + v1.x * c1 + v2.x * c2 + v3.x * c3;
            acc.y += v0.y * c0 + v1.y * c1 + v2.y * c2 + v3.y * c3;
        } else {
            acc.x += v0.x + v1.x + v2.x + v3.x;
            acc.y += v0.y + v1.y + v2.y + v3.y;
        }
    }
    for (; k < e2; ++k) {
        int si = csr_src[k];
        float2 vv = f[(size_t)si * 64 + lane];
        float c = HAS_SCALE ? scale[si] : 1.0f;
        acc.x += vv.x * c;
        acc.y += vv.y * c;
    }

    if (HAS_OUT) { float os = oscale[node]; acc.x *= os; acc.y *= os; }
    if (bias) {
        float2 bb = reinterpret_cast<const float2*>(bias)[lane];
        acc.x += bb.x; acc.y += bb.y;
    }
    reinterpret_cast<float2*>(outv)[(size_t)node * 64 + lane] = acc;
}

// Pack both W's fp32 -> hi/lo bf16 in MFMA-B fragment order (one dispatch).
// idx = ((nt*KT + kt)*64 + lane)*8 + j ; k = kt*32 + (lane>>4)*8 + j ; col = nt*16 + (lane&15)
__device__ __forceinline__ void pack_one(const float* __restrict__ W, short* __restrict__ hi,
                                         short* __restrict__ lo, int idx, int KT, int N) {
    int j = idx & 7;
    int l = (idx >> 3) & 63;
    int rest = idx >> 9;
    int kt = rest % KT;
    int nt = rest / KT;
    int k = kt * 32 + ((l >> 4) << 3) + j;
    int col = nt * 16 + (l & 15);
    float w = W[(size_t)k * N + col];
    unsigned u = __builtin_bit_cast(unsigned, w);
    hi[idx] = (short)(u >> 16);
    float hif = __builtin_bit_cast(float, u & 0xFFFF0000u);
    lo[idx] = (short)(__builtin_bit_cast(unsigned, w - hif) >> 16);
}

__global__ void k_pack_both(const float* __restrict__ W1, const float* __restrict__ W2,
                            short* __restrict__ h1, short* __restrict__ l1,
                            short* __restrict__ h2, short* __restrict__ l2) {
    int idx = blockIdx.x * blockDim.x + threadIdx.x;
    const int T1 = IN_DIM * HID_DIM;
    const int T2 = HID_DIM * OUT_DIM;
    if (idx < T1) pack_one(W1, h1, l1, idx, IN_DIM / 32, HID_DIM);
    else if (idx < T1 + T2) pack_one(W2, h2, l2, idx - T1, HID_DIM / 32, OUT_DIM);
}

// C[M x Nc] = epi( (rs_in ⊙ A[M x K]) @ W ), split-bf16 MFMA (hi*hi + lo*hi + hi*lo).
// Block: 256 thr = 4 waves; wave: 16 rows x 128 cols (8 col-tiles of 16x16x32).
template <int KT, bool HAS_RSIN, bool HAS_BIAS, bool RELU, bool HAS_RSOUT>
__global__ __launch_bounds__(256) void k_gemm_mfma(
    const float* __restrict__ A, const short* __restrict__ Bp_hi,
    const short* __restrict__ Bp_lo, const float* __restrict__ bias,
    const float* __restrict__ rs_in, const float* __restrict__ rs_out,
    float* __restrict__ C, int M, int Nc) {
    const int K = KT * 32;
    const int lane = threadIdx.x & 63;
    const int wave = threadIdx.x >> 6;
    const int row0 = blockIdx.y * 64 + wave * 16;
    const int colt0 = blockIdx.x * 8;

    int arow = row0 + (lane & 15);
    int ar = arow < M ? arow : M - 1;
    const int koff = (lane >> 4) << 3;
    const float rs = HAS_RSIN ? rs_in[ar] : 1.0f;

    f32x4 acc[8];
#pragma unroll
    for (int t = 0; t < 8; ++t) acc[t] = (f32x4){0.f, 0.f, 0.f, 0.f};

    const bf16x8* bh = reinterpret_cast<const bf16x8*>(Bp_hi);
    const bf16x8* bl = reinterpret_cast<const bf16x8*>(Bp_lo);

#pragma unroll
    for (int kt = 0; kt < KT; ++kt) {
        const float* ap = A + (size_t)ar * K + kt * 32 + koff;
        float av[8];
        *reinterpret_cast<float4*>(&av[0]) = *reinterpret_cast<const float4*>(ap);
        *reinterpret_cast<float4*>(&av[4]) = *reinterpret_cast<const float4*>(ap + 4);
        bf16x8 a_hi, a_lo;
#pragma unroll
        for (int j = 0; j < 8; ++j) {
            float a = av[j] * rs;
            unsigned u = __builtin_bit_cast(unsigned, a);
            a_hi[j] = (short)(u >> 16);
            float hif = __builtin_bit_cast(float, u & 0xFFFF0000u);
            a_lo[j] = (short)(__builtin_bit_cast(unsigned, a - hif) >> 16);
        }
#pragma unroll
        for (int ct = 0; ct < 8; ++ct) {
            int bidx = (colt0 + ct) * KT + kt;
            bf16x8 bhv = bh[bidx * 64 + lane];
            bf16x8 blv = bl[bidx * 64 + lane];
            acc[ct] = __builtin_amdgcn_mfma_f32_16x16x32_bf16(a_hi, bhv, acc[ct], 0, 0, 0);
            acc[ct] = __builtin_amdgcn_mfma_f32_16x16x32_bf16(a_lo, bhv, acc[ct], 0, 0, 0);
            acc[ct] = __builtin_amdgcn_mfma_f32_16x16x32_bf16(a_hi, blv, acc[ct], 0, 0, 0);
        }
    }

    const int crow0 = row0 + ((lane >> 4) << 2);
    float rso[4];
#pragma unroll
    for (int j = 0; j < 4; ++j)
        rso[j] = HAS_RSOUT ? ((crow0 + j < M) ? rs_out[crow0 + j] : 0.f) : 1.0f;

#pragma unroll
    for (int ct = 0; ct < 8; ++ct) {
        int col = (colt0 + ct) * 16 + (lane & 15);
        float bv = HAS_BIAS ? bias[col] : 0.f;
#pragma unroll
        for (int j = 0; j < 4; ++j) {
            int row = crow0 + j;
            if (row >= M) continue;
            float v = acc[ct][j] + bv;
            if (RELU) v = fmaxf(v, 0.f);
            v *= rso[j];
            C[(size_t)row * Nc + col] = v;
        }
    }
}

extern "C" void kernel_launch(void* const* d_in, const int* in_sizes, int n_in,
                              void* d_out, int out_size, void* d_ws, size_t ws_size,
                              hipStream_t stream) {
    const float* x  = (const float*)d_in[0];
    const int*   ei = (const int*)d_in[1];
    const float* W1 = (const float*)d_in[2];
    const float* b1 = (const float*)d_in[3];
    const float* W2 = (const float*)d_in[4];
    const float* b2 = (const float*)d_in[5];
    float* out = (float*)d_out;

    const int N = in_sizes[0] / IN_DIM;
    const int E = in_sizes[1] / 2;
    const int* src = ei;
    const int* dst = ei + E;

    char* ws = (char*)d_ws;
    size_t off = 0;
    auto alloc = [&](size_t bytes) {
        void* p = ws + off;
        off += (bytes + 255) & ~(size_t)255;
        return p;
    };
    int*   cnt_dst   = (int*)alloc((size_t)N * sizeof(int));
    float* out_isqrt = (float*)alloc((size_t)N * sizeof(float));
    float* in_isqrt  = (float*)alloc((size_t)N * sizeof(float));
    int*   row_off   = (int*)alloc((size_t)N * sizeof(int));
    int*   cursor    = (int*)alloc((size_t)N * sizeof(int));
    int*   scan_loc  = (int*)alloc((size_t)N * sizeof(int));
    int*   chunk_sum = (int*)alloc(64 * sizeof(int));
    int*   csr_src   = (int*)alloc((size_t)E * sizeof(int));
    short* W1p_hi    = (short*)alloc((size_t)IN_DIM * HID_DIM * sizeof(short));
    short* W1p_lo    = (short*)alloc((size_t)IN_DIM * HID_DIM * sizeof(short));
    short* W2p_hi    = (short*)alloc((size_t)HID_DIM * OUT_DIM * sizeof(short));
    short* W2p_lo    = (short*)alloc((size_t)HID_DIM * OUT_DIM * sizeof(short));
    float* m1 = (float*)alloc((size_t)N * IN_DIM * sizeof(float));
    float* h1 = (float*)alloc((size_t)N * HID_DIM * sizeof(float));
    float* t2 = (float*)alloc((size_t)N * OUT_DIM * sizeof(float));

    // partials (13.1 MB) overlay m1: dead before k_gather writes m1.
    unsigned* partials = (unsigned*)m1;

    const int thr = 256;
    const int nchunks = DIV_UP(N, 1024);  // 49

    // degrees + normalizers + CSR (no global atomics for counting)
    k_hist<<<dim3(HIST_G, 4), 256, 0, stream>>>(ei, E, partials);
    k_reduce_scan<<<nchunks, 256, 0, stream>>>(partials, cnt_dst, out_isqrt, in_isqrt,
                                               scan_loc, chunk_sum, N);
    k_scan_chunks<<<1, 64, 0, stream>>>(chunk_sum, nchunks);
    k_scan_apply<<<DIV_UP(N, 4 * thr), thr, 0, stream>>>(scan_loc, chunk_sum, row_off, cursor, N);
    k_fill_csr4<<<DIV_UP(E / 4, thr), thr, 0, stream>>>(src, dst, cursor, csr_src, E);

    // weight packing (fragment-ordered bf16 hi/lo), one dispatch
    k_pack_both<<<DIV_UP(IN_DIM * HID_DIM + HID_DIM * OUT_DIM, thr), thr, 0, stream>>>(
        W1, W2, W1p_hi, W1p_lo, W2p_hi, W2p_lo);

    // layer 1: m1 = (A+I)(out_isqrt ⊙ x); h1 = relu((in_isqrt ⊙ m1)@W1 + b1)
    k_gather<true, false><<<DIV_UP(N, 4), 256, 0, stream>>>(
        x, row_off, cnt_dst, csr_src, out_isqrt, nullptr, nullptr, m1, N);
    k_gemm_mfma<IN_DIM / 32, true, true, true, false>
        <<<dim3(HID_DIM / 128, DIV_UP(N, 64)), 256, 0, stream>>>(
            m1, W1p_hi, W1p_lo, b1, in_isqrt, nullptr, h1, N, HID_DIM);

    // layer 2: t2 = (h1@W2) ⊙ out_isqrt; out = in_isqrt ⊙ ((A+I) t2) + b2
    k_gemm_mfma<HID_DIM / 32, false, false, false, true>
        <<<dim3(OUT_DIM / 128, DIV_UP(N, 64)), 256, 0, stream>>>(
            h1, W2p_hi, W2p_lo, nullptr, nullptr, out_isqrt, t2, N, OUT_DIM);
    k_gather<false, true><<<DIV_UP(N, 4), 256, 0, stream>>>(
        t2, row_off, cnt_dst, csr_src, nullptr, in_isqrt, b2, out, N);
}